// Round 5
// baseline (1274.533 us; speedup 1.0000x reference)
//
#include <hip/hip_runtime.h>
#include <math.h>

#define NNODES 100000
#define NEDGES 1200000
#define HD 64
#define NLAYERS 8
#define NGRAPH 100

// ---------- order-preserving float<->uint encoding for atomicMax ----------
__device__ __forceinline__ unsigned enc_f(float f) {
    unsigned b = __float_as_uint(f);
    return (b & 0x80000000u) ? ~b : (b | 0x80000000u);
}
__device__ __forceinline__ float dec_f(unsigned u) {
    unsigned b = (u & 0x80000000u) ? (u ^ 0x80000000u) : ~u;
    return __uint_as_float(b);
}
// sentinel = enc(-inf) = 0x007FFFFF

// readlane: broadcast one lane's float to all lanes via SGPR (exec-independent)
__device__ __forceinline__ float rl(float v, int l) {
    return __uint_as_float(__builtin_amdgcn_readlane(__float_as_uint(v), l));
}

// ---------- lin0: x0 = relu(pos @ lin0_w + lin0_b) ----------
__global__ void lin0_k(const float* __restrict__ pos, const float* __restrict__ w,
                       const float* __restrict__ b, float* __restrict__ x0, int total) {
    int i = blockIdx.x * blockDim.x + threadIdx.x;
    if (i >= total) return;
    int n = i >> 6, h = i & 63;
    float p0 = pos[n * 3 + 0], p1 = pos[n * 3 + 1], p2 = pos[n * 3 + 2];
    float v = fmaf(p0, w[h], fmaf(p1, w[64 + h], fmaf(p2, w[128 + h], b[h])));
    x0[i] = fmaxf(v, 0.0f);
}

// ---------- CSR build ----------
// hist + rank fused: rank[e] = position of edge e within its dst bucket
__global__ void hist_k(const int* __restrict__ dst, int* __restrict__ deg,
                       int* __restrict__ rank, int E) {
    int e = blockIdx.x * blockDim.x + threadIdx.x;
    if (e < E) rank[e] = atomicAdd(&deg[dst[e]], 1);
}

__global__ void scan_part_k(const int* __restrict__ deg, int* __restrict__ bsum, int n) {
    __shared__ int s[256];
    int t = threadIdx.x;
    int i = blockIdx.x * 256 + t;
    s[t] = (i < n) ? deg[i] : 0;
    __syncthreads();
    for (int off = 128; off > 0; off >>= 1) {
        if (t < off) s[t] += s[t + off];
        __syncthreads();
    }
    if (t == 0) bsum[blockIdx.x] = s[0];
}

__global__ void scan_mid_k(const int* __restrict__ bsum, int* __restrict__ boff,
                           int nblk, int* __restrict__ roff, int n) {
    __shared__ int s[512];
    int t = threadIdx.x;
    int v = (t < nblk) ? bsum[t] : 0;
    s[t] = v;
    __syncthreads();
    for (int off = 1; off < 512; off <<= 1) {
        int u = (t >= off) ? s[t - off] : 0;
        __syncthreads();
        s[t] += u;
        __syncthreads();
    }
    if (t < nblk) boff[t] = s[t] - v;          // exclusive
    if (t == nblk - 1) roff[n] = s[t];         // == E
}

__global__ void scan_final_k(const int* __restrict__ deg, const int* __restrict__ boff,
                             int* __restrict__ roff, int n) {
    __shared__ int s[256];
    int t = threadIdx.x;
    int i = blockIdx.x * 256 + t;
    int v = (i < n) ? deg[i] : 0;
    s[t] = v;
    __syncthreads();
    for (int off = 1; off < 256; off <<= 1) {
        int u = (t >= off) ? s[t - off] : 0;
        __syncthreads();
        s[t] += u;
        __syncthreads();
    }
    if (i < n) roff[i] = boff[blockIdx.x] + s[t] - v;   // exclusive scan
}

// pure permute-write, no atomic (rank precomputed in hist_k)
__global__ void fill_k(const int* __restrict__ src, const int* __restrict__ dst,
                       const int* __restrict__ roff, const int* __restrict__ rank,
                       int* __restrict__ csr, int E) {
    int e = blockIdx.x * blockDim.x + threadIdx.x;
    if (e < E) csr[roff[dst[e]] + rank[e]] = src[e];
}

__global__ void init_pool_k(unsigned* __restrict__ pooled, int total) {
    int i = blockIdx.x * blockDim.x + threadIdx.x;
    if (i < total) pooled[i] = 0x007FFFFFu;   // enc(-inf)
}

// ---------- fused GCN2 layer: agg + residual + GEMM + relu ----------
// 4 nodes per wave. Folded M = (1-beta)*I + beta*W in LDS (swizzled M^T,
// conflict-free ds_read_b128, amortized over 4 nodes). h stays in VGPRs;
// broadcast via v_readlane (no LDS h traffic). Edge lists read via the
// scalar path (readfirstlane -> s_load), freeing VMEM for gathers.
#define GATHER(hb, nn)                                                        \
    {                                                                         \
        const int nu  = __builtin_amdgcn_readfirstlane(nn);                   \
        const int beg = roff[nu], end = roff[nu + 1];                         \
        float x0v = x0[(nu << 6) + lane];                                     \
        float s0 = 0.0f, s1 = 0.0f, s2 = 0.0f, s3 = 0.0f;                     \
        int i = beg;                                                          \
        for (; i + 4 <= end; i += 4) {                                        \
            int e0 = csr[i], e1 = csr[i + 1], e2 = csr[i + 2], e3 = csr[i + 3]; \
            s0 += xin[(e0 << 6) + lane];                                      \
            s1 += xin[(e1 << 6) + lane];                                      \
            s2 += xin[(e2 << 6) + lane];                                      \
            s3 += xin[(e3 << 6) + lane];                                      \
        }                                                                     \
        for (; i < end; ++i) s0 += xin[(csr[i] << 6) + lane];                 \
        hb = fmaf(0.9f, (s0 + s1) + (s2 + s3), 0.1f * x0v);                   \
    }

#define MLPSTEP(c, comp)                                                      \
    a0 = fmaf(rl(h0, 4 * g + c), mv.comp, a0);                                \
    a1 = fmaf(rl(h1, 4 * g + c), mv.comp, a1);                                \
    a2 = fmaf(rl(h2, 4 * g + c), mv.comp, a2);                                \
    a3 = fmaf(rl(h3, 4 * g + c), mv.comp, a3);

__global__ __launch_bounds__(256, 6) void layer_k(
    const float* __restrict__ xin, float* __restrict__ xout,
    const float* __restrict__ x0, const float* __restrict__ W,
    const int* __restrict__ roff, const int* __restrict__ csr,
    float beta, int total_waves) {
    __shared__ __align__(16) float MT[64 * 64];
    const int tid  = threadIdx.x;
    const int lane = tid & 63;
    const float omb = 1.0f - beta;
    for (int idx = tid; idx < 4096; idx += 256) {
        int k = idx >> 6, j = idx & 63;
        float m = beta * W[idx];
        if (k == j) m += omb;
        MT[j * 64 + (((k >> 2) ^ (j & 15)) << 2) + (k & 3)] = m;
    }
    __syncthreads();
    const int wid0 = (blockIdx.x * blockDim.x + tid) >> 6;
    for (int grp = wid0; grp < NNODES / 4; grp += total_waves) {
        const int nb = grp << 2;
        float h0, h1, h2, h3;
        GATHER(h0, nb + 0)
        GATHER(h1, nb + 1)
        GATHER(h2, nb + 2)
        GATHER(h3, nb + 3)
        float a0 = 0.0f, a1 = 0.0f, a2 = 0.0f, a3 = 0.0f;
#pragma unroll
        for (int g = 0; g < 16; ++g) {
            float4 mv = *(const float4*)&MT[(lane << 6) + ((g ^ (lane & 15)) << 2)];
            MLPSTEP(0, x)
            MLPSTEP(1, y)
            MLPSTEP(2, z)
            MLPSTEP(3, w)
        }
        xout[((nb + 0) << 6) + lane] = fmaxf(a0, 0.0f);
        xout[((nb + 1) << 6) + lane] = fmaxf(a1, 0.0f);
        xout[((nb + 2) << 6) + lane] = fmaxf(a2, 0.0f);
        xout[((nb + 3) << 6) + lane] = fmaxf(a3, 0.0f);
    }
}

// ---------- lin1 + segment_max pooling fused (same scheme) ----------
__global__ __launch_bounds__(256, 6) void lin1pool_k(
    const float* __restrict__ xin, const float* __restrict__ W,
    const float* __restrict__ bvec, const int* __restrict__ batch,
    unsigned* __restrict__ pooled, int total_waves) {
    __shared__ __align__(16) float MT[64 * 64];
    const int tid  = threadIdx.x;
    const int lane = tid & 63;
    for (int idx = tid; idx < 4096; idx += 256) {
        int k = idx >> 6, j = idx & 63;
        MT[j * 64 + (((k >> 2) ^ (j & 15)) << 2) + (k & 3)] = W[idx];
    }
    __syncthreads();
    const float bias = bvec[lane];
    const int wid0 = (blockIdx.x * blockDim.x + tid) >> 6;
    for (int grp = wid0; grp < NNODES / 4; grp += total_waves) {
        const int nb = grp << 2;
        float h0 = xin[((nb + 0) << 6) + lane];
        float h1 = xin[((nb + 1) << 6) + lane];
        float h2 = xin[((nb + 2) << 6) + lane];
        float h3 = xin[((nb + 3) << 6) + lane];
        int gi0 = batch[nb + 0], gi1 = batch[nb + 1];
        int gi2 = batch[nb + 2], gi3 = batch[nb + 3];
        float a0 = bias, a1 = bias, a2 = bias, a3 = bias;
#pragma unroll
        for (int g = 0; g < 16; ++g) {
            float4 mv = *(const float4*)&MT[(lane << 6) + ((g ^ (lane & 15)) << 2)];
            MLPSTEP(0, x)
            MLPSTEP(1, y)
            MLPSTEP(2, z)
            MLPSTEP(3, w)
        }
        atomicMax(&pooled[(gi0 << 6) + lane], enc_f(a0));
        atomicMax(&pooled[(gi1 << 6) + lane], enc_f(a1));
        atomicMax(&pooled[(gi2 << 6) + lane], enc_f(a2));
        atomicMax(&pooled[(gi3 << 6) + lane], enc_f(a3));
    }
}

// ---------- head: MLP + BN + out + log_softmax, single block ----------
__global__ __launch_bounds__(256) void head_k(
    const unsigned* __restrict__ pooled,
    const float* __restrict__ m1w, const float* __restrict__ m1b,
    const float* __restrict__ g1, const float* __restrict__ be1,
    const float* __restrict__ m2w, const float* __restrict__ m2b,
    const float* __restrict__ g2, const float* __restrict__ be2,
    const float* __restrict__ ow, const float* __restrict__ ob,
    float* __restrict__ out) {
    __shared__ float A[NGRAPH * 64];
    __shared__ float B[NGRAPH * 64];
    __shared__ float mu[64], rs[64];
    __shared__ float LG[NGRAPH * 10];
    int t = threadIdx.x;
    for (int i = t; i < NGRAPH * 64; i += 256) {
        float f = dec_f(pooled[i]);
        if (!isfinite(f)) f = 0.0f;   // empty-segment guard
        A[i] = f;
    }
    __syncthreads();
    // ---- mlp1 ----
    for (int i = t; i < NGRAPH * 64; i += 256) {
        int g = i >> 6, j = i & 63;
        float acc = m1b[j];
        for (int k = 0; k < 64; ++k) acc = fmaf(A[(g << 6) + k], m1w[k * 64 + j], acc);
        B[i] = acc;
    }
    __syncthreads();
    if (t < 64) {
        float sm = 0.0f, sq = 0.0f;
        for (int g = 0; g < NGRAPH; ++g) { float z = B[g * 64 + t]; sm += z; sq += z * z; }
        float m = sm * (1.0f / NGRAPH);
        float var = sq * (1.0f / NGRAPH) - m * m;
        mu[t] = m; rs[t] = rsqrtf(var + 1e-5f);
    }
    __syncthreads();
    for (int i = t; i < NGRAPH * 64; i += 256) {
        int j = i & 63;
        float z = fmaf((B[i] - mu[j]) * rs[j], g1[j], be1[j]);
        A[i] = fmaxf(z, 0.0f);
    }
    __syncthreads();
    // ---- mlp2 ----
    for (int i = t; i < NGRAPH * 64; i += 256) {
        int g = i >> 6, j = i & 63;
        float acc = m2b[j];
        for (int k = 0; k < 64; ++k) acc = fmaf(A[(g << 6) + k], m2w[k * 64 + j], acc);
        B[i] = acc;
    }
    __syncthreads();
    if (t < 64) {
        float sm = 0.0f, sq = 0.0f;
        for (int g = 0; g < NGRAPH; ++g) { float z = B[g * 64 + t]; sm += z; sq += z * z; }
        float m = sm * (1.0f / NGRAPH);
        float var = sq * (1.0f / NGRAPH) - m * m;
        mu[t] = m; rs[t] = rsqrtf(var + 1e-5f);
    }
    __syncthreads();
    for (int i = t; i < NGRAPH * 64; i += 256) {
        int j = i & 63;
        float z = fmaf((B[i] - mu[j]) * rs[j], g2[j], be2[j]);
        A[i] = fmaxf(z, 0.0f);
    }
    __syncthreads();
    // ---- out + log_softmax ----
    for (int i = t; i < NGRAPH * 10; i += 256) {
        int g = i / 10, j = i - g * 10;
        float acc = ob[j];
        for (int k = 0; k < 64; ++k) acc = fmaf(A[(g << 6) + k], ow[k * 10 + j], acc);
        LG[i] = acc;
    }
    __syncthreads();
    if (t < NGRAPH) {
        float m = -1e30f;
        for (int j = 0; j < 10; ++j) m = fmaxf(m, LG[t * 10 + j]);
        float s = 0.0f;
        for (int j = 0; j < 10; ++j) s += expf(LG[t * 10 + j] - m);
        float lse = m + logf(s);
        for (int j = 0; j < 10; ++j) out[t * 10 + j] = LG[t * 10 + j] - lse;
    }
}

extern "C" void kernel_launch(void* const* d_in, const int* in_sizes, int n_in,
                              void* d_out, int out_size, void* d_ws, size_t ws_size,
                              hipStream_t stream) {
    const float* pos   = (const float*)d_in[0];
    const int*   eidx  = (const int*)d_in[1];
    const int*   batch = (const int*)d_in[2];
    const float* l0w   = (const float*)d_in[3];
    const float* l0b   = (const float*)d_in[4];
    const float* cw    = (const float*)d_in[5];
    const float* l1w   = (const float*)d_in[6];
    const float* l1b   = (const float*)d_in[7];
    const float* m1w   = (const float*)d_in[8];
    const float* m1b   = (const float*)d_in[9];
    const float* g1    = (const float*)d_in[10];
    const float* b1    = (const float*)d_in[11];
    const float* m2w   = (const float*)d_in[12];
    const float* m2b   = (const float*)d_in[13];
    const float* g2    = (const float*)d_in[14];
    const float* b2    = (const float*)d_in[15];
    const float* ow    = (const float*)d_in[16];
    const float* ob    = (const float*)d_in[17];
    float* out = (float*)d_out;
    const int* src = eidx;
    const int* dst = eidx + NEDGES;

    size_t off = 0;
    auto alloc = [&](size_t bytes) -> void* {
        void* p = (char*)d_ws + off;
        off += (bytes + 255) & ~(size_t)255;
        return p;
    };
    float*    x0     = (float*)alloc((size_t)NNODES * 64 * 4);
    float*    xA     = (float*)alloc((size_t)NNODES * 64 * 4);
    float*    xB     = (float*)alloc((size_t)NNODES * 64 * 4);
    int*      deg    = (int*)alloc((size_t)NNODES * 4);
    int*      roff   = (int*)alloc((size_t)(NNODES + 1) * 4);
    const int NBLK   = (NNODES + 255) / 256;                     // 391
    int*      bsum   = (int*)alloc((size_t)NBLK * 4);
    int*      boff   = (int*)alloc((size_t)NBLK * 4);
    int*      csr    = (int*)alloc((size_t)NEDGES * 4);
    unsigned* pooled = (unsigned*)alloc((size_t)NGRAPH * 64 * 4);
    int*      rank   = (int*)xB;   // xB is dead until layer 1 writes it

    hipMemsetAsync(deg, 0, (size_t)NNODES * 4, stream);
    {
        int total = NNODES * 64;
        lin0_k<<<(total + 255) / 256, 256, 0, stream>>>(pos, l0w, l0b, x0, total);
    }
    hist_k<<<(NEDGES + 255) / 256, 256, 0, stream>>>(dst, deg, rank, NEDGES);
    scan_part_k<<<NBLK, 256, 0, stream>>>(deg, bsum, NNODES);
    scan_mid_k<<<1, 512, 0, stream>>>(bsum, boff, NBLK, roff, NNODES);
    scan_final_k<<<NBLK, 256, 0, stream>>>(deg, boff, roff, NNODES);
    fill_k<<<(NEDGES + 255) / 256, 256, 0, stream>>>(src, dst, roff, rank, csr, NEDGES);
    init_pool_k<<<(NGRAPH * 64 + 255) / 256, 256, 0, stream>>>(pooled, NGRAPH * 64);

    const int LBLOCKS = 2048;
    const int TW = LBLOCKS * 256 / 64;   // total waves = 8192
    const float* cur = x0;
    for (int l = 0; l < NLAYERS; ++l) {
        float beta = (float)log(0.5 / (double)(l + 1) + 1.0);
        float* nxt = (l & 1) ? xB : xA;
        layer_k<<<LBLOCKS, 256, 0, stream>>>(cur, nxt, x0, cw + (size_t)l * 4096,
                                             roff, csr, beta, TW);
        cur = nxt;
    }
    lin1pool_k<<<LBLOCKS, 256, 0, stream>>>(cur, l1w, l1b, batch, pooled, TW);
    head_k<<<1, 256, 0, stream>>>(pooled, m1w, m1b, g1, b1, m2w, m2b, g2, b2, ow, ob, out);
}

// Round 6
// 682.112 us; speedup vs baseline: 1.8685x; 1.8685x over previous
//
#include <hip/hip_runtime.h>
#include <math.h>

#define NNODES 100000
#define NEDGES 1200000
#define HD 64
#define NLAYERS 8
#define NGRAPH 100

// ---------- lin0: x0 = relu(pos @ lin0_w + lin0_b) ----------
__global__ void lin0_k(const float* __restrict__ pos, const float* __restrict__ w,
                       const float* __restrict__ b, float* __restrict__ x0, int total) {
    int i = blockIdx.x * blockDim.x + threadIdx.x;
    if (i >= total) return;
    int n = i >> 6, h = i & 63;
    float p0 = pos[n * 3 + 0], p1 = pos[n * 3 + 1], p2 = pos[n * 3 + 2];
    float v = fmaf(p0, w[h], fmaf(p1, w[64 + h], fmaf(p2, w[128 + h], b[h])));
    x0[i] = fmaxf(v, 0.0f);
}

// ---------- CSR build ----------
// hist + rank fused: rank[e] = position of edge e within its dst bucket
__global__ void hist_k(const int* __restrict__ dst, int* __restrict__ deg,
                       int* __restrict__ rank, int E) {
    int e = blockIdx.x * blockDim.x + threadIdx.x;
    if (e < E) rank[e] = atomicAdd(&deg[dst[e]], 1);
}

__global__ void scan_part_k(const int* __restrict__ deg, int* __restrict__ bsum, int n) {
    __shared__ int s[256];
    int t = threadIdx.x;
    int i = blockIdx.x * 256 + t;
    s[t] = (i < n) ? deg[i] : 0;
    __syncthreads();
    for (int off = 128; off > 0; off >>= 1) {
        if (t < off) s[t] += s[t + off];
        __syncthreads();
    }
    if (t == 0) bsum[blockIdx.x] = s[0];
}

__global__ void scan_mid_k(const int* __restrict__ bsum, int* __restrict__ boff,
                           int nblk, int* __restrict__ roff, int n) {
    __shared__ int s[512];
    int t = threadIdx.x;
    int v = (t < nblk) ? bsum[t] : 0;
    s[t] = v;
    __syncthreads();
    for (int off = 1; off < 512; off <<= 1) {
        int u = (t >= off) ? s[t - off] : 0;
        __syncthreads();
        s[t] += u;
        __syncthreads();
    }
    if (t < nblk) boff[t] = s[t] - v;          // exclusive
    if (t == nblk - 1) roff[n] = s[t];         // == E
}

__global__ void scan_final_k(const int* __restrict__ deg, const int* __restrict__ boff,
                             int* __restrict__ roff, int n) {
    __shared__ int s[256];
    int t = threadIdx.x;
    int i = blockIdx.x * 256 + t;
    int v = (i < n) ? deg[i] : 0;
    s[t] = v;
    __syncthreads();
    for (int off = 1; off < 256; off <<= 1) {
        int u = (t >= off) ? s[t - off] : 0;
        __syncthreads();
        s[t] += u;
        __syncthreads();
    }
    if (i < n) roff[i] = boff[blockIdx.x] + s[t] - v;   // exclusive scan
}

// pure permute-write, no atomic (rank precomputed in hist_k)
__global__ void fill_k(const int* __restrict__ src, const int* __restrict__ dst,
                       const int* __restrict__ roff, const int* __restrict__ rank,
                       int* __restrict__ csr, int E) {
    int e = blockIdx.x * blockDim.x + threadIdx.x;
    if (e < E) csr[roff[dst[e]] + rank[e]] = src[e];
}

// ---------- fused GCN2 layer: agg + residual + GEMM + relu ----------
// One wave per node (round-4 proven structure). Folded M = (1-beta)*I + beta*W
// in LDS as swizzled M^T -> conflict-free ds_read_b128:
//   MT idx = j*64 + ((k>>2 ^ (j&15))<<2) + (k&3)
// h broadcast via per-wave LDS slot (same-address reads are free).
// 8-wide gather unroll for more outstanding loads per wave.
__global__ __launch_bounds__(256, 8) void layer_k(
    const float* __restrict__ xin, float* __restrict__ xout,
    const float* __restrict__ x0, const float* __restrict__ W,
    const int* __restrict__ roff, const int* __restrict__ csr,
    float beta, int total_waves) {
    __shared__ __align__(16) float MT[64 * 64];
    __shared__ __align__(16) float hrow[4][64];
    const int tid   = threadIdx.x;
    const int lane  = tid & 63;
    const int wslot = tid >> 6;
    const float omb = 1.0f - beta;
    for (int idx = tid; idx < 4096; idx += 256) {
        int k = idx >> 6, j = idx & 63;
        float m = beta * W[idx];
        if (k == j) m += omb;
        MT[j * 64 + (((k >> 2) ^ (j & 15)) << 2) + (k & 3)] = m;
    }
    __syncthreads();
    const int wid0 = (blockIdx.x * blockDim.x + tid) >> 6;
    for (int n = wid0; n < NNODES; n += total_waves) {
        const int beg = roff[n], end = roff[n + 1];
        float x0v = x0[(n << 6) + lane];      // issue early, overlaps gather
        float s0 = 0.0f, s1 = 0.0f, s2 = 0.0f, s3 = 0.0f;
        int i = beg;
        for (; i + 8 <= end; i += 8) {
            int e0 = csr[i + 0], e1 = csr[i + 1], e2 = csr[i + 2], e3 = csr[i + 3];
            int e4 = csr[i + 4], e5 = csr[i + 5], e6 = csr[i + 6], e7 = csr[i + 7];
            float a0 = xin[(e0 << 6) + lane];
            float a1 = xin[(e1 << 6) + lane];
            float a2 = xin[(e2 << 6) + lane];
            float a3 = xin[(e3 << 6) + lane];
            float a4 = xin[(e4 << 6) + lane];
            float a5 = xin[(e5 << 6) + lane];
            float a6 = xin[(e6 << 6) + lane];
            float a7 = xin[(e7 << 6) + lane];
            s0 += a0; s1 += a1; s2 += a2; s3 += a3;
            s0 += a4; s1 += a5; s2 += a6; s3 += a7;
        }
        for (; i + 4 <= end; i += 4) {
            int e0 = csr[i + 0], e1 = csr[i + 1], e2 = csr[i + 2], e3 = csr[i + 3];
            s0 += xin[(e0 << 6) + lane];
            s1 += xin[(e1 << 6) + lane];
            s2 += xin[(e2 << 6) + lane];
            s3 += xin[(e3 << 6) + lane];
        }
        for (; i < end; ++i) s0 += xin[(csr[i] << 6) + lane];
        float agg = (s0 + s1) + (s2 + s3);
        float h = fmaf(0.9f, agg, 0.1f * x0v);
        hrow[wslot][lane] = h;
        __builtin_amdgcn_wave_barrier();   // wave-internal LDS RAW; DS in-order per wave
        float a0 = 0.0f, a1 = 0.0f, a2 = 0.0f, a3 = 0.0f;
#pragma unroll
        for (int g = 0; g < 16; ++g) {
            float4 hv = *(const float4*)&hrow[wslot][g * 4];                  // broadcast
            float4 mv = *(const float4*)&MT[(lane << 6) + ((g ^ (lane & 15)) << 2)];
            a0 = fmaf(hv.x, mv.x, a0);
            a1 = fmaf(hv.y, mv.y, a1);
            a2 = fmaf(hv.z, mv.z, a2);
            a3 = fmaf(hv.w, mv.w, a3);
        }
        __builtin_amdgcn_wave_barrier();   // keep next iter's write after these reads
        float o = (a0 + a1) + (a2 + a3);   // identity already folded into M
        xout[(n << 6) + lane] = fmaxf(o, 0.0f);
    }
}

// ---------- lin1 + segment_max pooling, ZERO atomics ----------
// batch is sorted: block (g,part) binary-searches its node range, computes the
// lin1 MLP per node, keeps a register running max, combines waves in LDS.
__device__ __forceinline__ int lbound(const int* __restrict__ a, int n, int v) {
    int lo = 0, hi = n;
    while (lo < hi) { int mid = (lo + hi) >> 1; if (a[mid] < v) lo = mid + 1; else hi = mid; }
    return lo;
}

__global__ __launch_bounds__(256, 8) void poolpart_k(
    const float* __restrict__ xin, const float* __restrict__ W,
    const float* __restrict__ bvec, const int* __restrict__ batch,
    float* __restrict__ pmax) {
    __shared__ __align__(16) float MT[64 * 64];
    __shared__ __align__(16) float hrow[4][64];
    __shared__ float wm[4][64];
    const int tid   = threadIdx.x;
    const int lane  = tid & 63;
    const int wslot = tid >> 6;
    for (int idx = tid; idx < 4096; idx += 256) {
        int k = idx >> 6, j = idx & 63;
        MT[j * 64 + (((k >> 2) ^ (j & 15)) << 2) + (k & 3)] = W[idx];
    }
    __syncthreads();
    const int g = blockIdx.x >> 2, part = blockIdx.x & 3;
    const int lo = lbound(batch, NNODES, g);
    const int hi = lbound(batch, NNODES, g + 1);
    const int cnt = hi - lo;
    const int qlo = lo + (cnt * part) / 4;
    const int qhi = lo + (cnt * (part + 1)) / 4;
    const float bias = bvec[lane];
    float vmax = -INFINITY;
    for (int n = qlo + wslot; n < qhi; n += 4) {
        hrow[wslot][lane] = xin[(n << 6) + lane];
        __builtin_amdgcn_wave_barrier();
        float a0 = bias, a1 = 0.0f, a2 = 0.0f, a3 = 0.0f;
#pragma unroll
        for (int gg = 0; gg < 16; ++gg) {
            float4 hv = *(const float4*)&hrow[wslot][gg * 4];
            float4 mv = *(const float4*)&MT[(lane << 6) + ((gg ^ (lane & 15)) << 2)];
            a0 = fmaf(hv.x, mv.x, a0);
            a1 = fmaf(hv.y, mv.y, a1);
            a2 = fmaf(hv.z, mv.z, a2);
            a3 = fmaf(hv.w, mv.w, a3);
        }
        __builtin_amdgcn_wave_barrier();
        vmax = fmaxf(vmax, (a0 + a1) + (a2 + a3));
    }
    wm[wslot][lane] = vmax;
    __syncthreads();
    if (tid < 64) {
        float m = fmaxf(fmaxf(wm[0][tid], wm[1][tid]), fmaxf(wm[2][tid], wm[3][tid]));
        pmax[blockIdx.x * 64 + tid] = m;
    }
}

__global__ void poolcomb_k(const float* __restrict__ pmax, float* __restrict__ pooled) {
    int i = blockIdx.x * blockDim.x + threadIdx.x;
    if (i >= NGRAPH * 64) return;
    int g = i >> 6, lane = i & 63;
    float m = fmaxf(fmaxf(pmax[(4 * g + 0) * 64 + lane], pmax[(4 * g + 1) * 64 + lane]),
                    fmaxf(pmax[(4 * g + 2) * 64 + lane], pmax[(4 * g + 3) * 64 + lane]));
    pooled[i] = m;   // may be -inf for empty graphs; head guards
}

// ---------- head: MLP + BN + out + log_softmax, single block ----------
__global__ __launch_bounds__(256) void head_k(
    const float* __restrict__ pooled,
    const float* __restrict__ m1w, const float* __restrict__ m1b,
    const float* __restrict__ g1, const float* __restrict__ be1,
    const float* __restrict__ m2w, const float* __restrict__ m2b,
    const float* __restrict__ g2, const float* __restrict__ be2,
    const float* __restrict__ ow, const float* __restrict__ ob,
    float* __restrict__ out) {
    __shared__ float A[NGRAPH * 64];
    __shared__ float B[NGRAPH * 64];
    __shared__ float mu[64], rs[64];
    __shared__ float LG[NGRAPH * 10];
    int t = threadIdx.x;
    for (int i = t; i < NGRAPH * 64; i += 256) {
        float f = pooled[i];
        if (!isfinite(f)) f = 0.0f;   // empty-segment guard
        A[i] = f;
    }
    __syncthreads();
    // ---- mlp1 ----
    for (int i = t; i < NGRAPH * 64; i += 256) {
        int g = i >> 6, j = i & 63;
        float acc = m1b[j];
        for (int k = 0; k < 64; ++k) acc = fmaf(A[(g << 6) + k], m1w[k * 64 + j], acc);
        B[i] = acc;
    }
    __syncthreads();
    if (t < 64) {
        float sm = 0.0f, sq = 0.0f;
        for (int g = 0; g < NGRAPH; ++g) { float z = B[g * 64 + t]; sm += z; sq += z * z; }
        float m = sm * (1.0f / NGRAPH);
        float var = sq * (1.0f / NGRAPH) - m * m;
        mu[t] = m; rs[t] = rsqrtf(var + 1e-5f);
    }
    __syncthreads();
    for (int i = t; i < NGRAPH * 64; i += 256) {
        int j = i & 63;
        float z = fmaf((B[i] - mu[j]) * rs[j], g1[j], be1[j]);
        A[i] = fmaxf(z, 0.0f);
    }
    __syncthreads();
    // ---- mlp2 ----
    for (int i = t; i < NGRAPH * 64; i += 256) {
        int g = i >> 6, j = i & 63;
        float acc = m2b[j];
        for (int k = 0; k < 64; ++k) acc = fmaf(A[(g << 6) + k], m2w[k * 64 + j], acc);
        B[i] = acc;
    }
    __syncthreads();
    if (t < 64) {
        float sm = 0.0f, sq = 0.0f;
        for (int g = 0; g < NGRAPH; ++g) { float z = B[g * 64 + t]; sm += z; sq += z * z; }
        float m = sm * (1.0f / NGRAPH);
        float var = sq * (1.0f / NGRAPH) - m * m;
        mu[t] = m; rs[t] = rsqrtf(var + 1e-5f);
    }
    __syncthreads();
    for (int i = t; i < NGRAPH * 64; i += 256) {
        int j = i & 63;
        float z = fmaf((B[i] - mu[j]) * rs[j], g2[j], be2[j]);
        A[i] = fmaxf(z, 0.0f);
    }
    __syncthreads();
    // ---- out + log_softmax ----
    for (int i = t; i < NGRAPH * 10; i += 256) {
        int g = i / 10, j = i - g * 10;
        float acc = ob[j];
        for (int k = 0; k < 64; ++k) acc = fmaf(A[(g << 6) + k], ow[k * 10 + j], acc);
        LG[i] = acc;
    }
    __syncthreads();
    if (t < NGRAPH) {
        float m = -1e30f;
        for (int j = 0; j < 10; ++j) m = fmaxf(m, LG[t * 10 + j]);
        float s = 0.0f;
        for (int j = 0; j < 10; ++j) s += expf(LG[t * 10 + j] - m);
        float lse = m + logf(s);
        for (int j = 0; j < 10; ++j) out[t * 10 + j] = LG[t * 10 + j] - lse;
    }
}

extern "C" void kernel_launch(void* const* d_in, const int* in_sizes, int n_in,
                              void* d_out, int out_size, void* d_ws, size_t ws_size,
                              hipStream_t stream) {
    const float* pos   = (const float*)d_in[0];
    const int*   eidx  = (const int*)d_in[1];
    const int*   batch = (const int*)d_in[2];
    const float* l0w   = (const float*)d_in[3];
    const float* l0b   = (const float*)d_in[4];
    const float* cw    = (const float*)d_in[5];
    const float* l1w   = (const float*)d_in[6];
    const float* l1b   = (const float*)d_in[7];
    const float* m1w   = (const float*)d_in[8];
    const float* m1b   = (const float*)d_in[9];
    const float* g1    = (const float*)d_in[10];
    const float* b1    = (const float*)d_in[11];
    const float* m2w   = (const float*)d_in[12];
    const float* m2b   = (const float*)d_in[13];
    const float* g2    = (const float*)d_in[14];
    const float* b2    = (const float*)d_in[15];
    const float* ow    = (const float*)d_in[16];
    const float* ob    = (const float*)d_in[17];
    float* out = (float*)d_out;
    const int* src = eidx;
    const int* dst = eidx + NEDGES;

    size_t off = 0;
    auto alloc = [&](size_t bytes) -> void* {
        void* p = (char*)d_ws + off;
        off += (bytes + 255) & ~(size_t)255;
        return p;
    };
    float*    x0     = (float*)alloc((size_t)NNODES * 64 * 4);
    float*    xA     = (float*)alloc((size_t)NNODES * 64 * 4);
    float*    xB     = (float*)alloc((size_t)NNODES * 64 * 4);
    int*      deg    = (int*)alloc((size_t)NNODES * 4);
    int*      roff   = (int*)alloc((size_t)(NNODES + 1) * 4);
    const int NBLK   = (NNODES + 255) / 256;                     // 391
    int*      bsum   = (int*)alloc((size_t)NBLK * 4);
    int*      boff   = (int*)alloc((size_t)NBLK * 4);
    int*      csr    = (int*)alloc((size_t)NEDGES * 4);
    float*    pooled = (float*)alloc((size_t)NGRAPH * 64 * 4);
    float*    pmax   = (float*)alloc((size_t)NGRAPH * 4 * 64 * 4);
    int*      rank   = (int*)xB;   // xB is dead until layer 1 writes it

    hipMemsetAsync(deg, 0, (size_t)NNODES * 4, stream);
    {
        int total = NNODES * 64;
        lin0_k<<<(total + 255) / 256, 256, 0, stream>>>(pos, l0w, l0b, x0, total);
    }
    hist_k<<<(NEDGES + 255) / 256, 256, 0, stream>>>(dst, deg, rank, NEDGES);
    scan_part_k<<<NBLK, 256, 0, stream>>>(deg, bsum, NNODES);
    scan_mid_k<<<1, 512, 0, stream>>>(bsum, boff, NBLK, roff, NNODES);
    scan_final_k<<<NBLK, 256, 0, stream>>>(deg, boff, roff, NNODES);
    fill_k<<<(NEDGES + 255) / 256, 256, 0, stream>>>(src, dst, roff, rank, csr, NEDGES);

    const int LBLOCKS = 2048;
    const int TW = LBLOCKS * 256 / 64;   // total waves = 8192
    const float* cur = x0;
    for (int l = 0; l < NLAYERS; ++l) {
        float beta = (float)log(0.5 / (double)(l + 1) + 1.0);
        float* nxt = (l & 1) ? xB : xA;
        layer_k<<<LBLOCKS, 256, 0, stream>>>(cur, nxt, x0, cw + (size_t)l * 4096,
                                             roff, csr, beta, TW);
        cur = nxt;
    }
    poolpart_k<<<NGRAPH * 4, 256, 0, stream>>>(cur, l1w, l1b, batch, pmax);
    poolcomb_k<<<(NGRAPH * 64 + 255) / 256, 256, 0, stream>>>(pmax, pooled);
    head_k<<<1, 256, 0, stream>>>(pooled, m1w, m1b, g1, b1, m2w, m2b, g2, b2, ow, ob, out);
}

// Round 8
// 650.744 us; speedup vs baseline: 1.9586x; 1.0482x over previous
//
#include <hip/hip_runtime.h>
#include <math.h>

#define NNODES 100000
#define NEDGES 1200000
#define HD 64
#define NLAYERS 8
#define NGRAPH 100
#define PPART 32   // pooling partitions per graph

// ---------- lin0: x0 = relu(pos @ lin0_w + lin0_b) ----------
__global__ void lin0_k(const float* __restrict__ pos, const float* __restrict__ w,
                       const float* __restrict__ b, float* __restrict__ x0, int total) {
    int i = blockIdx.x * blockDim.x + threadIdx.x;
    if (i >= total) return;
    int n = i >> 6, h = i & 63;
    float p0 = pos[n * 3 + 0], p1 = pos[n * 3 + 1], p2 = pos[n * 3 + 2];
    float v = fmaf(p0, w[h], fmaf(p1, w[64 + h], fmaf(p2, w[128 + h], b[h])));
    x0[i] = fmaxf(v, 0.0f);
}

// ---------- CSR build ----------
// hist + rank fused: rank[e] = position of edge e within its dst bucket
__global__ void hist_k(const int* __restrict__ dst, int* __restrict__ deg,
                       int* __restrict__ rank, int E) {
    int e = blockIdx.x * blockDim.x + threadIdx.x;
    if (e < E) rank[e] = atomicAdd(&deg[dst[e]], 1);
}

__global__ void scan_part_k(const int* __restrict__ deg, int* __restrict__ bsum, int n) {
    __shared__ int s[256];
    int t = threadIdx.x;
    int i = blockIdx.x * 256 + t;
    s[t] = (i < n) ? deg[i] : 0;
    __syncthreads();
    for (int off = 128; off > 0; off >>= 1) {
        if (t < off) s[t] += s[t + off];
        __syncthreads();
    }
    if (t == 0) bsum[blockIdx.x] = s[0];
}

__global__ void scan_mid_k(const int* __restrict__ bsum, int* __restrict__ boff,
                           int nblk, int* __restrict__ roff, int n) {
    __shared__ int s[512];
    int t = threadIdx.x;
    int v = (t < nblk) ? bsum[t] : 0;
    s[t] = v;
    __syncthreads();
    for (int off = 1; off < 512; off <<= 1) {
        int u = (t >= off) ? s[t - off] : 0;
        __syncthreads();
        s[t] += u;
        __syncthreads();
    }
    if (t < nblk) boff[t] = s[t] - v;          // exclusive
    if (t == nblk - 1) roff[n] = s[t];         // == E
}

__global__ void scan_final_k(const int* __restrict__ deg, const int* __restrict__ boff,
                             int* __restrict__ roff, int n) {
    __shared__ int s[256];
    int t = threadIdx.x;
    int i = blockIdx.x * 256 + t;
    int v = (i < n) ? deg[i] : 0;
    s[t] = v;
    __syncthreads();
    for (int off = 1; off < 256; off <<= 1) {
        int u = (t >= off) ? s[t - off] : 0;
        __syncthreads();
        s[t] += u;
        __syncthreads();
    }
    if (i < n) roff[i] = boff[blockIdx.x] + s[t] - v;   // exclusive scan
}

// pure permute-write, no atomic (rank precomputed in hist_k)
__global__ void fill_k(const int* __restrict__ src, const int* __restrict__ dst,
                       const int* __restrict__ roff, const int* __restrict__ rank,
                       int* __restrict__ csr, int E) {
    int e = blockIdx.x * blockDim.x + threadIdx.x;
    if (e < E) csr[roff[dst[e]] + rank[e]] = src[e];
}

// ---------- fused GCN2 layer: agg + residual + GEMM + relu ----------
// One wave per node (round-4/6 proven structure, f32 storage).
// Folded M = (1-beta)*I + beta*W in LDS as swizzled M^T -> conflict-free
// ds_read_b128:  MT idx = j*64 + ((k>>2 ^ (j&15))<<2) + (k&3)
// h broadcast via per-wave LDS slot (same-address reads are free).
__global__ __launch_bounds__(256, 8) void layer_k(
    const float* __restrict__ xin, float* __restrict__ xout,
    const float* __restrict__ x0, const float* __restrict__ W,
    const int* __restrict__ roff, const int* __restrict__ csr,
    float beta, int total_waves) {
    __shared__ __align__(16) float MT[64 * 64];
    __shared__ __align__(16) float hrow[4][64];
    const int tid   = threadIdx.x;
    const int lane  = tid & 63;
    const int wslot = tid >> 6;
    const float omb = 1.0f - beta;
    for (int idx = tid; idx < 4096; idx += 256) {
        int k = idx >> 6, j = idx & 63;
        float m = beta * W[idx];
        if (k == j) m += omb;
        MT[j * 64 + (((k >> 2) ^ (j & 15)) << 2) + (k & 3)] = m;
    }
    __syncthreads();
    const int wid0 = (blockIdx.x * blockDim.x + tid) >> 6;
    for (int n = wid0; n < NNODES; n += total_waves) {
        const int beg = roff[n], end = roff[n + 1];
        float x0v = x0[(n << 6) + lane];      // issue early, overlaps gather
        float s0 = 0.0f, s1 = 0.0f, s2 = 0.0f, s3 = 0.0f;
        int i = beg;
        for (; i + 8 <= end; i += 8) {
            int e0 = csr[i + 0], e1 = csr[i + 1], e2 = csr[i + 2], e3 = csr[i + 3];
            int e4 = csr[i + 4], e5 = csr[i + 5], e6 = csr[i + 6], e7 = csr[i + 7];
            float a0 = xin[(e0 << 6) + lane];
            float a1 = xin[(e1 << 6) + lane];
            float a2 = xin[(e2 << 6) + lane];
            float a3 = xin[(e3 << 6) + lane];
            float a4 = xin[(e4 << 6) + lane];
            float a5 = xin[(e5 << 6) + lane];
            float a6 = xin[(e6 << 6) + lane];
            float a7 = xin[(e7 << 6) + lane];
            s0 += a0; s1 += a1; s2 += a2; s3 += a3;
            s0 += a4; s1 += a5; s2 += a6; s3 += a7;
        }
        for (; i + 4 <= end; i += 4) {
            int e0 = csr[i + 0], e1 = csr[i + 1], e2 = csr[i + 2], e3 = csr[i + 3];
            s0 += xin[(e0 << 6) + lane];
            s1 += xin[(e1 << 6) + lane];
            s2 += xin[(e2 << 6) + lane];
            s3 += xin[(e3 << 6) + lane];
        }
        for (; i < end; ++i) s0 += xin[(csr[i] << 6) + lane];
        float agg = (s0 + s1) + (s2 + s3);
        float h = fmaf(0.9f, agg, 0.1f * x0v);
        hrow[wslot][lane] = h;
        __builtin_amdgcn_wave_barrier();   // wave-internal LDS RAW; DS in-order per wave
        float a0 = 0.0f, a1 = 0.0f, a2 = 0.0f, a3 = 0.0f;
#pragma unroll
        for (int g = 0; g < 16; ++g) {
            float4 hv = *(const float4*)&hrow[wslot][g * 4];                  // broadcast
            float4 mv = *(const float4*)&MT[(lane << 6) + ((g ^ (lane & 15)) << 2)];
            a0 = fmaf(hv.x, mv.x, a0);
            a1 = fmaf(hv.y, mv.y, a1);
            a2 = fmaf(hv.z, mv.z, a2);
            a3 = fmaf(hv.w, mv.w, a3);
        }
        __builtin_amdgcn_wave_barrier();   // keep next iter's write after these reads
        float o = (a0 + a1) + (a2 + a3);   // identity already folded into M
        xout[(n << 6) + lane] = fmaxf(o, 0.0f);
    }
}

// ---------- lin1 + segment_max pooling, ZERO atomics, 32 partitions ----------
__device__ __forceinline__ int lbound(const int* __restrict__ a, int n, int v) {
    int lo = 0, hi = n;
    while (lo < hi) { int mid = (lo + hi) >> 1; if (a[mid] < v) lo = mid + 1; else hi = mid; }
    return lo;
}

__global__ __launch_bounds__(256, 8) void poolpart_k(
    const float* __restrict__ xin, const float* __restrict__ W,
    const float* __restrict__ bvec, const int* __restrict__ batch,
    float* __restrict__ pmax) {
    __shared__ __align__(16) float MT[64 * 64];
    __shared__ __align__(16) float hrow[4][64];
    __shared__ float wm[4][64];
    const int tid   = threadIdx.x;
    const int lane  = tid & 63;
    const int wslot = tid >> 6;
    for (int idx = tid; idx < 4096; idx += 256) {
        int k = idx >> 6, j = idx & 63;
        MT[j * 64 + (((k >> 2) ^ (j & 15)) << 2) + (k & 3)] = W[idx];
    }
    __syncthreads();
    const int g = blockIdx.x / PPART, part = blockIdx.x % PPART;
    const int lo = lbound(batch, NNODES, g);
    const int hi = lbound(batch, NNODES, g + 1);
    const int cnt = hi - lo;
    const int qlo = lo + (cnt * part) / PPART;
    const int qhi = lo + (cnt * (part + 1)) / PPART;
    const float bias = bvec[lane];
    float vmax = -INFINITY;
    for (int n = qlo + wslot; n < qhi; n += 4) {
        hrow[wslot][lane] = xin[(n << 6) + lane];
        __builtin_amdgcn_wave_barrier();
        float a0 = bias, a1 = 0.0f, a2 = 0.0f, a3 = 0.0f;
#pragma unroll
        for (int gg = 0; gg < 16; ++gg) {
            float4 hv = *(const float4*)&hrow[wslot][gg * 4];
            float4 mv = *(const float4*)&MT[(lane << 6) + ((gg ^ (lane & 15)) << 2)];
            a0 = fmaf(hv.x, mv.x, a0);
            a1 = fmaf(hv.y, mv.y, a1);
            a2 = fmaf(hv.z, mv.z, a2);
            a3 = fmaf(hv.w, mv.w, a3);
        }
        __builtin_amdgcn_wave_barrier();
        vmax = fmaxf(vmax, (a0 + a1) + (a2 + a3));
    }
    wm[wslot][lane] = vmax;
    __syncthreads();
    if (tid < 64) {
        float m = fmaxf(fmaxf(wm[0][tid], wm[1][tid]), fmaxf(wm[2][tid], wm[3][tid]));
        pmax[blockIdx.x * 64 + tid] = m;
    }
}

__global__ void poolcomb_k(const float* __restrict__ pmax, float* __restrict__ pooled) {
    int i = blockIdx.x * blockDim.x + threadIdx.x;
    if (i >= NGRAPH * 64) return;
    int g = i >> 6, lane = i & 63;
    float m = -INFINITY;
    for (int p = 0; p < PPART; ++p)
        m = fmaxf(m, pmax[(PPART * g + p) * 64 + lane]);
    pooled[i] = m;   // may be -inf for empty graphs; head guards
}

// ---------- head: MLP + BN + out + log_softmax, single block ----------
__global__ __launch_bounds__(256) void head_k(
    const float* __restrict__ pooled,
    const float* __restrict__ m1w, const float* __restrict__ m1b,
    const float* __restrict__ g1, const float* __restrict__ be1,
    const float* __restrict__ m2w, const float* __restrict__ m2b,
    const float* __restrict__ g2, const float* __restrict__ be2,
    const float* __restrict__ ow, const float* __restrict__ ob,
    float* __restrict__ out) {
    __shared__ float A[NGRAPH * 64];
    __shared__ float B[NGRAPH * 64];
    __shared__ float mu[64], rs[64];
    __shared__ float LG[NGRAPH * 10];
    int t = threadIdx.x;
    for (int i = t; i < NGRAPH * 64; i += 256) {
        float f = pooled[i];
        if (!isfinite(f)) f = 0.0f;   // empty-segment guard
        A[i] = f;
    }
    __syncthreads();
    // ---- mlp1 ----
    for (int i = t; i < NGRAPH * 64; i += 256) {
        int g = i >> 6, j = i & 63;
        float acc = m1b[j];
        for (int k = 0; k < 64; ++k) acc = fmaf(A[(g << 6) + k], m1w[k * 64 + j], acc);
        B[i] = acc;
    }
    __syncthreads();
    if (t < 64) {
        float sm = 0.0f, sq = 0.0f;
        for (int g = 0; g < NGRAPH; ++g) { float z = B[g * 64 + t]; sm += z; sq += z * z; }
        float m = sm * (1.0f / NGRAPH);
        float var = sq * (1.0f / NGRAPH) - m * m;
        mu[t] = m; rs[t] = rsqrtf(var + 1e-5f);
    }
    __syncthreads();
    for (int i = t; i < NGRAPH * 64; i += 256) {
        int j = i & 63;
        float z = fmaf((B[i] - mu[j]) * rs[j], g1[j], be1[j]);
        A[i] = fmaxf(z, 0.0f);
    }
    __syncthreads();
    // ---- mlp2 ----
    for (int i = t; i < NGRAPH * 64; i += 256) {
        int g = i >> 6, j = i & 63;
        float acc = m2b[j];
        for (int k = 0; k < 64; ++k) acc = fmaf(A[(g << 6) + k], m2w[k * 64 + j], acc);
        B[i] = acc;
    }
    __syncthreads();
    if (t < 64) {
        float sm = 0.0f, sq = 0.0f;
        for (int g = 0; g < NGRAPH; ++g) { float z = B[g * 64 + t]; sm += z; sq += z * z; }
        float m = sm * (1.0f / NGRAPH);
        float var = sq * (1.0f / NGRAPH) - m * m;
        mu[t] = m; rs[t] = rsqrtf(var + 1e-5f);
    }
    __syncthreads();
    for (int i = t; i < NGRAPH * 64; i += 256) {
        int j = i & 63;
        float z = fmaf((B[i] - mu[j]) * rs[j], g2[j], be2[j]);
        A[i] = fmaxf(z, 0.0f);
    }
    __syncthreads();
    // ---- out + log_softmax ----
    for (int i = t; i < NGRAPH * 10; i += 256) {
        int g = i / 10, j = i - g * 10;
        float acc = ob[j];
        for (int k = 0; k < 64; ++k) acc = fmaf(A[(g << 6) + k], ow[k * 10 + j], acc);
        LG[i] = acc;
    }
    __syncthreads();
    if (t < NGRAPH) {
        float m = -1e30f;
        for (int j = 0; j < 10; ++j) m = fmaxf(m, LG[t * 10 + j]);
        float s = 0.0f;
        for (int j = 0; j < 10; ++j) s += expf(LG[t * 10 + j] - m);
        float lse = m + logf(s);
        for (int j = 0; j < 10; ++j) out[t * 10 + j] = LG[t * 10 + j] - lse;
    }
}

extern "C" void kernel_launch(void* const* d_in, const int* in_sizes, int n_in,
                              void* d_out, int out_size, void* d_ws, size_t ws_size,
                              hipStream_t stream) {
    const float* pos   = (const float*)d_in[0];
    const int*   eidx  = (const int*)d_in[1];
    const int*   batch = (const int*)d_in[2];
    const float* l0w   = (const float*)d_in[3];
    const float* l0b   = (const float*)d_in[4];
    const float* cw    = (const float*)d_in[5];
    const float* l1w   = (const float*)d_in[6];
    const float* l1b   = (const float*)d_in[7];
    const float* m1w   = (const float*)d_in[8];
    const float* m1b   = (const float*)d_in[9];
    const float* g1    = (const float*)d_in[10];
    const float* b1    = (const float*)d_in[11];
    const float* m2w   = (const float*)d_in[12];
    const float* m2b   = (const float*)d_in[13];
    const float* g2    = (const float*)d_in[14];
    const float* b2    = (const float*)d_in[15];
    const float* ow    = (const float*)d_in[16];
    const float* ob    = (const float*)d_in[17];
    float* out = (float*)d_out;
    const int* src = eidx;
    const int* dst = eidx + NEDGES;

    size_t off = 0;
    auto alloc = [&](size_t bytes) -> void* {
        void* p = (char*)d_ws + off;
        off += (bytes + 255) & ~(size_t)255;
        return p;
    };
    float*    x0     = (float*)alloc((size_t)NNODES * 64 * 4);
    float*    xA     = (float*)alloc((size_t)NNODES * 64 * 4);
    float*    xB     = (float*)alloc((size_t)NNODES * 64 * 4);
    int*      deg    = (int*)alloc((size_t)NNODES * 4);
    int*      roff   = (int*)alloc((size_t)(NNODES + 1) * 4);
    const int NBLK   = (NNODES + 255) / 256;                     // 391
    int*      bsum   = (int*)alloc((size_t)NBLK * 4);
    int*      boff   = (int*)alloc((size_t)NBLK * 4);
    int*      csr    = (int*)alloc((size_t)NEDGES * 4);
    float*    pooled = (float*)alloc((size_t)NGRAPH * 64 * 4);
    float*    pmax   = (float*)alloc((size_t)NGRAPH * PPART * 64 * 4);
    int*      rank   = (int*)xB;   // xB dead until layer 1 writes it

    hipMemsetAsync(deg, 0, (size_t)NNODES * 4, stream);
    {
        int total = NNODES * 64;
        lin0_k<<<(total + 255) / 256, 256, 0, stream>>>(pos, l0w, l0b, x0, total);
    }
    hist_k<<<(NEDGES + 255) / 256, 256, 0, stream>>>(dst, deg, rank, NEDGES);
    scan_part_k<<<NBLK, 256, 0, stream>>>(deg, bsum, NNODES);
    scan_mid_k<<<1, 512, 0, stream>>>(bsum, boff, NBLK, roff, NNODES);
    scan_final_k<<<NBLK, 256, 0, stream>>>(deg, boff, roff, NNODES);
    fill_k<<<(NEDGES + 255) / 256, 256, 0, stream>>>(src, dst, roff, rank, csr, NEDGES);

    const int LBLOCKS = 2048;
    const int TW = LBLOCKS * 256 / 64;   // total waves = 8192
    const float* cur = x0;
    for (int l = 0; l < NLAYERS; ++l) {
        float beta = (float)log(0.5 / (double)(l + 1) + 1.0);
        float* nxt = (l & 1) ? xB : xA;
        layer_k<<<LBLOCKS, 256, 0, stream>>>(cur, nxt, x0, cw + (size_t)l * 4096,
                                             roff, csr, beta, TW);
        cur = nxt;
    }
    poolpart_k<<<NGRAPH * PPART, 256, 0, stream>>>(cur, l1w, l1b, batch, pmax);
    poolcomb_k<<<(NGRAPH * 64 + 255) / 256, 256, 0, stream>>>(pmax, pooled);
    head_k<<<1, 256, 0, stream>>>(pooled, m1w, m1b, g1, b1, m2w, m2b, g2, b2, ow, ob, out);
}

// Round 9
// 620.868 us; speedup vs baseline: 2.0528x; 1.0481x over previous
//
#include <hip/hip_runtime.h>
#include <hip/hip_fp16.h>
#include <math.h>

#define NNODES 100000
#define NEDGES 1200000
#define HD 64
#define NLAYERS 8
#define NGRAPH 100
#define PPART 32          // pooling partitions per graph
#define C8 16777216.0f    // 8^8 = 2^24, exact in f32

// ---------- fp16 storage helpers (arithmetic stays f32) ----------
__device__ __forceinline__ float h2f(__half h) { return __half2float(h); }
__device__ __forceinline__ __half f2h(float f) { return __float2half(f); }  // RNE

// ---------- lin0: x0 = relu(pos @ lin0_w + lin0_b), f32 + fp16 copies ----------
__global__ void lin0_k(const float* __restrict__ pos, const float* __restrict__ w,
                       const float* __restrict__ b, float* __restrict__ x0f,
                       __half* __restrict__ x0h, int total) {
    int i = blockIdx.x * blockDim.x + threadIdx.x;
    if (i >= total) return;
    int n = i >> 6, h = i & 63;
    float p0 = pos[n * 3 + 0], p1 = pos[n * 3 + 1], p2 = pos[n * 3 + 2];
    float v = fmaf(p0, w[h], fmaf(p1, w[64 + h], fmaf(p2, w[128 + h], b[h])));
    v = fmaxf(v, 0.0f);
    x0f[i] = v;
    x0h[i] = f2h(v);      // layer-0 input, scale c_0 = 1
}

// ---------- CSR build ----------
__global__ void hist_k(const int* __restrict__ dst, int* __restrict__ deg,
                       int* __restrict__ rank, int E) {
    int e = blockIdx.x * blockDim.x + threadIdx.x;
    if (e < E) rank[e] = atomicAdd(&deg[dst[e]], 1);
}

__global__ void scan_part_k(const int* __restrict__ deg, int* __restrict__ bsum, int n) {
    __shared__ int s[256];
    int t = threadIdx.x;
    int i = blockIdx.x * 256 + t;
    s[t] = (i < n) ? deg[i] : 0;
    __syncthreads();
    for (int off = 128; off > 0; off >>= 1) {
        if (t < off) s[t] += s[t + off];
        __syncthreads();
    }
    if (t == 0) bsum[blockIdx.x] = s[0];
}

__global__ void scan_mid_k(const int* __restrict__ bsum, int* __restrict__ boff,
                           int nblk, int* __restrict__ roff, int n) {
    __shared__ int s[512];
    int t = threadIdx.x;
    int v = (t < nblk) ? bsum[t] : 0;
    s[t] = v;
    __syncthreads();
    for (int off = 1; off < 512; off <<= 1) {
        int u = (t >= off) ? s[t - off] : 0;
        __syncthreads();
        s[t] += u;
        __syncthreads();
    }
    if (t < nblk) boff[t] = s[t] - v;          // exclusive
    if (t == nblk - 1) roff[n] = s[t];         // == E
}

__global__ void scan_final_k(const int* __restrict__ deg, const int* __restrict__ boff,
                             int* __restrict__ roff, int n) {
    __shared__ int s[256];
    int t = threadIdx.x;
    int i = blockIdx.x * 256 + t;
    int v = (i < n) ? deg[i] : 0;
    s[t] = v;
    __syncthreads();
    for (int off = 1; off < 256; off <<= 1) {
        int u = (t >= off) ? s[t - off] : 0;
        __syncthreads();
        s[t] += u;
        __syncthreads();
    }
    if (i < n) roff[i] = boff[blockIdx.x] + s[t] - v;   // exclusive scan
}

// pure permute-write, no atomic (rank precomputed in hist_k)
__global__ void fill_k(const int* __restrict__ src, const int* __restrict__ dst,
                       const int* __restrict__ roff, const int* __restrict__ rank,
                       int* __restrict__ csr, int E) {
    int e = blockIdx.x * blockDim.x + threadIdx.x;
    if (e < E) csr[roff[dst[e]] + rank[e]] = src[e];
}

// ---------- fused GCN2 layer: agg + residual + GEMM + relu ----------
// One wave per node (round-4/6 proven structure). Node features stored fp16
// at scale x'_l = x_l / 8^l (relu is positively homogeneous, so the exact
// power-of-2 rescale r=1/8 folds into M with zero extra rounding/VALU).
// M_folded = (1/8) * ((1-beta)*I + beta*W) in LDS as swizzled M^T ->
// conflict-free ds_read_b128. x0 residual term scaled by 0.1/8^l (f32 exact).
__global__ __launch_bounds__(256, 8) void layer_k(
    const __half* __restrict__ xin, __half* __restrict__ xout,
    const float* __restrict__ x0, const float* __restrict__ W,
    const int* __restrict__ roff, const int* __restrict__ csr,
    float beta, float x0scale, int total_waves) {
    __shared__ __align__(16) float MT[64 * 64];
    __shared__ __align__(16) float hrow[4][64];
    const int tid   = threadIdx.x;
    const int lane  = tid & 63;
    const int wslot = tid >> 6;
    const float omb = 1.0f - beta;
    for (int idx = tid; idx < 4096; idx += 256) {
        int k = idx >> 6, j = idx & 63;
        float m = beta * W[idx];
        if (k == j) m += omb;
        m *= 0.125f;                           // fold r = 1/8 (exact)
        MT[j * 64 + (((k >> 2) ^ (j & 15)) << 2) + (k & 3)] = m;
    }
    __syncthreads();
    const int wid0 = (blockIdx.x * blockDim.x + tid) >> 6;
    for (int n = wid0; n < NNODES; n += total_waves) {
        const int beg = roff[n], end = roff[n + 1];
        float x0v = x0[(n << 6) + lane];      // issue early, overlaps gather
        float s0 = 0.0f, s1 = 0.0f, s2 = 0.0f, s3 = 0.0f;
        int i = beg;
        for (; i + 8 <= end; i += 8) {
            int e0 = csr[i + 0], e1 = csr[i + 1], e2 = csr[i + 2], e3 = csr[i + 3];
            int e4 = csr[i + 4], e5 = csr[i + 5], e6 = csr[i + 6], e7 = csr[i + 7];
            __half a0 = xin[(e0 << 6) + lane];
            __half a1 = xin[(e1 << 6) + lane];
            __half a2 = xin[(e2 << 6) + lane];
            __half a3 = xin[(e3 << 6) + lane];
            __half a4 = xin[(e4 << 6) + lane];
            __half a5 = xin[(e5 << 6) + lane];
            __half a6 = xin[(e6 << 6) + lane];
            __half a7 = xin[(e7 << 6) + lane];
            s0 += h2f(a0); s1 += h2f(a1); s2 += h2f(a2); s3 += h2f(a3);
            s0 += h2f(a4); s1 += h2f(a5); s2 += h2f(a6); s3 += h2f(a7);
        }
        for (; i + 4 <= end; i += 4) {
            int e0 = csr[i + 0], e1 = csr[i + 1], e2 = csr[i + 2], e3 = csr[i + 3];
            s0 += h2f(xin[(e0 << 6) + lane]);
            s1 += h2f(xin[(e1 << 6) + lane]);
            s2 += h2f(xin[(e2 << 6) + lane]);
            s3 += h2f(xin[(e3 << 6) + lane]);
        }
        for (; i < end; ++i) s0 += h2f(xin[(csr[i] << 6) + lane]);
        float agg = (s0 + s1) + (s2 + s3);
        float h = fmaf(0.9f, agg, x0scale * x0v);
        hrow[wslot][lane] = h;
        __builtin_amdgcn_wave_barrier();   // wave-internal LDS RAW; DS in-order per wave
        float a0 = 0.0f, a1 = 0.0f, a2 = 0.0f, a3 = 0.0f;
#pragma unroll
        for (int g = 0; g < 16; ++g) {
            float4 hv = *(const float4*)&hrow[wslot][g * 4];                  // broadcast
            float4 mv = *(const float4*)&MT[(lane << 6) + ((g ^ (lane & 15)) << 2)];
            a0 = fmaf(hv.x, mv.x, a0);
            a1 = fmaf(hv.y, mv.y, a1);
            a2 = fmaf(hv.z, mv.z, a2);
            a3 = fmaf(hv.w, mv.w, a3);
        }
        __builtin_amdgcn_wave_barrier();   // keep next iter's write after these reads
        float o = (a0 + a1) + (a2 + a3);   // identity + r already folded into M
        xout[(n << 6) + lane] = f2h(fmaxf(o, 0.0f));
    }
}

// ---------- lin1 + segment_max pooling, ZERO atomics, 32 partitions ----------
__device__ __forceinline__ int lbound(const int* __restrict__ a, int n, int v) {
    int lo = 0, hi = n;
    while (lo < hi) { int mid = (lo + hi) >> 1; if (a[mid] < v) lo = mid + 1; else hi = mid; }
    return lo;
}

__global__ __launch_bounds__(256, 8) void poolpart_k(
    const __half* __restrict__ xin, const float* __restrict__ W,
    const float* __restrict__ bvec, const int* __restrict__ batch,
    float* __restrict__ pmax) {
    __shared__ __align__(16) float MT[64 * 64];
    __shared__ __align__(16) float hrow[4][64];
    __shared__ float wm[4][64];
    const int tid   = threadIdx.x;
    const int lane  = tid & 63;
    const int wslot = tid >> 6;
    for (int idx = tid; idx < 4096; idx += 256) {
        int k = idx >> 6, j = idx & 63;
        MT[j * 64 + (((k >> 2) ^ (j & 15)) << 2) + (k & 3)] = W[idx];
    }
    __syncthreads();
    const int g = blockIdx.x / PPART, part = blockIdx.x % PPART;
    const int lo = lbound(batch, NNODES, g);
    const int hi = lbound(batch, NNODES, g + 1);
    const int cnt = hi - lo;
    const int qlo = lo + (cnt * part) / PPART;
    const int qhi = lo + (cnt * (part + 1)) / PPART;
    const float bias = bvec[lane];
    float vmax = -INFINITY;
    for (int n = qlo + wslot; n < qhi; n += 4) {
        hrow[wslot][lane] = h2f(xin[(n << 6) + lane]);   // stored units (x/8^8)
        __builtin_amdgcn_wave_barrier();
        float a0 = 0.0f, a1 = 0.0f, a2 = 0.0f, a3 = 0.0f;
#pragma unroll
        for (int gg = 0; gg < 16; ++gg) {
            float4 hv = *(const float4*)&hrow[wslot][gg * 4];
            float4 mv = *(const float4*)&MT[(lane << 6) + ((gg ^ (lane & 15)) << 2)];
            a0 = fmaf(hv.x, mv.x, a0);
            a1 = fmaf(hv.y, mv.y, a1);
            a2 = fmaf(hv.z, mv.z, a2);
            a3 = fmaf(hv.w, mv.w, a3);
        }
        __builtin_amdgcn_wave_barrier();
        float acc = (a0 + a1) + (a2 + a3);
        vmax = fmaxf(vmax, fmaf(C8, acc, bias));         // undo 8^8 scale (exact 2^24)
    }
    wm[wslot][lane] = vmax;
    __syncthreads();
    if (tid < 64) {
        float m = fmaxf(fmaxf(wm[0][tid], wm[1][tid]), fmaxf(wm[2][tid], wm[3][tid]));
        pmax[blockIdx.x * 64 + tid] = m;
    }
}

__global__ void poolcomb_k(const float* __restrict__ pmax, float* __restrict__ pooled) {
    int i = blockIdx.x * blockDim.x + threadIdx.x;
    if (i >= NGRAPH * 64) return;
    int g = i >> 6, lane = i & 63;
    float m = -INFINITY;
    for (int p = 0; p < PPART; ++p)
        m = fmaxf(m, pmax[(PPART * g + p) * 64 + lane]);
    pooled[i] = m;   // may be -inf for empty graphs; head guards
}

// ---------- head: MLP + BN + out + log_softmax, single block ----------
__global__ __launch_bounds__(256) void head_k(
    const float* __restrict__ pooled,
    const float* __restrict__ m1w, const float* __restrict__ m1b,
    const float* __restrict__ g1, const float* __restrict__ be1,
    const float* __restrict__ m2w, const float* __restrict__ m2b,
    const float* __restrict__ g2, const float* __restrict__ be2,
    const float* __restrict__ ow, const float* __restrict__ ob,
    float* __restrict__ out) {
    __shared__ float A[NGRAPH * 64];
    __shared__ float B[NGRAPH * 64];
    __shared__ float mu[64], rs[64];
    __shared__ float LG[NGRAPH * 10];
    int t = threadIdx.x;
    for (int i = t; i < NGRAPH * 64; i += 256) {
        float f = pooled[i];
        if (!isfinite(f)) f = 0.0f;   // empty-segment guard
        A[i] = f;
    }
    __syncthreads();
    // ---- mlp1 ----
    for (int i = t; i < NGRAPH * 64; i += 256) {
        int g = i >> 6, j = i & 63;
        float acc = m1b[j];
        for (int k = 0; k < 64; ++k) acc = fmaf(A[(g << 6) + k], m1w[k * 64 + j], acc);
        B[i] = acc;
    }
    __syncthreads();
    if (t < 64) {
        float sm = 0.0f, sq = 0.0f;
        for (int g = 0; g < NGRAPH; ++g) { float z = B[g * 64 + t]; sm += z; sq += z * z; }
        float m = sm * (1.0f / NGRAPH);
        float var = sq * (1.0f / NGRAPH) - m * m;
        mu[t] = m; rs[t] = rsqrtf(var + 1e-5f);
    }
    __syncthreads();
    for (int i = t; i < NGRAPH * 64; i += 256) {
        int j = i & 63;
        float z = fmaf((B[i] - mu[j]) * rs[j], g1[j], be1[j]);
        A[i] = fmaxf(z, 0.0f);
    }
    __syncthreads();
    // ---- mlp2 ----
    for (int i = t; i < NGRAPH * 64; i += 256) {
        int g = i >> 6, j = i & 63;
        float acc = m2b[j];
        for (int k = 0; k < 64; ++k) acc = fmaf(A[(g << 6) + k], m2w[k * 64 + j], acc);
        B[i] = acc;
    }
    __syncthreads();
    if (t < 64) {
        float sm = 0.0f, sq = 0.0f;
        for (int g = 0; g < NGRAPH; ++g) { float z = B[g * 64 + t]; sm += z; sq += z * z; }
        float m = sm * (1.0f / NGRAPH);
        float var = sq * (1.0f / NGRAPH) - m * m;
        mu[t] = m; rs[t] = rsqrtf(var + 1e-5f);
    }
    __syncthreads();
    for (int i = t; i < NGRAPH * 64; i += 256) {
        int j = i & 63;
        float z = fmaf((B[i] - mu[j]) * rs[j], g2[j], be2[j]);
        A[i] = fmaxf(z, 0.0f);
    }
    __syncthreads();
    // ---- out + log_softmax ----
    for (int i = t; i < NGRAPH * 10; i += 256) {
        int g = i / 10, j = i - g * 10;
        float acc = ob[j];
        for (int k = 0; k < 64; ++k) acc = fmaf(A[(g << 6) + k], ow[k * 10 + j], acc);
        LG[i] = acc;
    }
    __syncthreads();
    if (t < NGRAPH) {
        float m = -1e30f;
        for (int j = 0; j < 10; ++j) m = fmaxf(m, LG[t * 10 + j]);
        float s = 0.0f;
        for (int j = 0; j < 10; ++j) s += expf(LG[t * 10 + j] - m);
        float lse = m + logf(s);
        for (int j = 0; j < 10; ++j) out[t * 10 + j] = LG[t * 10 + j] - lse;
    }
}

extern "C" void kernel_launch(void* const* d_in, const int* in_sizes, int n_in,
                              void* d_out, int out_size, void* d_ws, size_t ws_size,
                              hipStream_t stream) {
    const float* pos   = (const float*)d_in[0];
    const int*   eidx  = (const int*)d_in[1];
    const int*   batch = (const int*)d_in[2];
    const float* l0w   = (const float*)d_in[3];
    const float* l0b   = (const float*)d_in[4];
    const float* cw    = (const float*)d_in[5];
    const float* l1w   = (const float*)d_in[6];
    const float* l1b   = (const float*)d_in[7];
    const float* m1w   = (const float*)d_in[8];
    const float* m1b   = (const float*)d_in[9];
    const float* g1    = (const float*)d_in[10];
    const float* b1    = (const float*)d_in[11];
    const float* m2w   = (const float*)d_in[12];
    const float* m2b   = (const float*)d_in[13];
    const float* g2    = (const float*)d_in[14];
    const float* b2    = (const float*)d_in[15];
    const float* ow    = (const float*)d_in[16];
    const float* ob    = (const float*)d_in[17];
    float* out = (float*)d_out;
    const int* src = eidx;
    const int* dst = eidx + NEDGES;

    size_t off = 0;
    auto alloc = [&](size_t bytes) -> void* {
        void* p = (char*)d_ws + off;
        off += (bytes + 255) & ~(size_t)255;
        return p;
    };
    float*  x0f    = (float*)alloc((size_t)NNODES * 64 * 4);
    __half* x0h    = (__half*)alloc((size_t)NNODES * 64 * 2);
    __half* xA     = (__half*)alloc((size_t)NNODES * 64 * 2);
    __half* xB     = (__half*)alloc((size_t)NNODES * 64 * 2);
    int*    deg    = (int*)alloc((size_t)NNODES * 4);
    int*    roff   = (int*)alloc((size_t)(NNODES + 1) * 4);
    const int NBLK = (NNODES + 255) / 256;                     // 391
    int*    bsum   = (int*)alloc((size_t)NBLK * 4);
    int*    boff   = (int*)alloc((size_t)NBLK * 4);
    int*    csr    = (int*)alloc((size_t)NEDGES * 4);
    float*  pooled = (float*)alloc((size_t)NGRAPH * 64 * 4);
    float*  pmax   = (float*)alloc((size_t)NGRAPH * PPART * 64 * 4);
    int*    rank   = (int*)xB;   // xB (12.8MB) dead until layer 1 writes it; rank needs 4.8MB

    hipMemsetAsync(deg, 0, (size_t)NNODES * 4, stream);
    {
        int total = NNODES * 64;
        lin0_k<<<(total + 255) / 256, 256, 0, stream>>>(pos, l0w, l0b, x0f, x0h, total);
    }
    hist_k<<<(NEDGES + 255) / 256, 256, 0, stream>>>(dst, deg, rank, NEDGES);
    scan_part_k<<<NBLK, 256, 0, stream>>>(deg, bsum, NNODES);
    scan_mid_k<<<1, 512, 0, stream>>>(bsum, boff, NBLK, roff, NNODES);
    scan_final_k<<<NBLK, 256, 0, stream>>>(deg, boff, roff, NNODES);
    fill_k<<<(NEDGES + 255) / 256, 256, 0, stream>>>(src, dst, roff, rank, csr, NEDGES);

    const int LBLOCKS = 2048;
    const int TW = LBLOCKS * 256 / 64;   // total waves = 8192
    const __half* cur = x0h;
    for (int l = 0; l < NLAYERS; ++l) {
        float beta    = (float)log(0.5 / (double)(l + 1) + 1.0);
        float x0scale = (float)(0.1 * ldexp(1.0, -3 * l));   // 0.1 / 8^l, exact scale chain
        __half* nxt = (l & 1) ? xB : xA;
        layer_k<<<LBLOCKS, 256, 0, stream>>>(cur, nxt, x0f, cw + (size_t)l * 4096,
                                             roff, csr, beta, x0scale, TW);
        cur = nxt;
    }
    poolpart_k<<<NGRAPH * PPART, 256, 0, stream>>>(cur, l1w, l1b, batch, pmax);
    poolcomb_k<<<(NGRAPH * 64 + 255) / 256, 256, 0, stream>>>(pmax, pooled);
    head_k<<<1, 256, 0, stream>>>(pooled, m1w, m1b, g1, b1, m2w, m2b, g2, b2, ow, ob, out);
}